// Round 16
// baseline (166.109 us; speedup 1.0000x reference)
//
#include <hip/hip_runtime.h>
#include <hip/hip_bf16.h>

#define NH 128   // hidden
#define NC 384   // edge feature dim
#define NK 32    // neighbors
#define FFN_NPB 20   // nodes per ffn block: 500 blocks -> ~1.95/CU, near-perfect balance

typedef __attribute__((ext_vector_type(8))) short short8v;   // 8 bf16
typedef __attribute__((ext_vector_type(4))) float f32x4;

#define MFMA16(a, b, c) __builtin_amdgcn_mfma_f32_16x16x32_bf16((a), (b), (c), 0, 0, 0)

__device__ __forceinline__ ushort f2bf(float x) {
  __hip_bfloat16 h = __float2bfloat16(x);   // RNE; packs to v_cvt_pk_bf16_f32
  ushort u;
  __builtin_memcpy(&u, &h, 2);
  return u;
}

__device__ __forceinline__ short8v ld8(const ushort* p) {
  return *reinterpret_cast<const short8v*>(p);
}
__device__ __forceinline__ void st8(ushort* p, short8v v) {
  *reinterpret_cast<short8v*>(p) = v;
}

__device__ __forceinline__ short8v pack8(float4 a, float4 b) {
  short8v v;
  v[0] = (short)f2bf(a.x); v[1] = (short)f2bf(a.y);
  v[2] = (short)f2bf(a.z); v[3] = (short)f2bf(a.w);
  v[4] = (short)f2bf(b.x); v[5] = (short)f2bf(b.y);
  v[6] = (short)f2bf(b.z); v[7] = (short)f2bf(b.w);
  return v;
}

// gelu(x) = x * sigmoid(x*(1.5958 + 0.07136 x^2)); |err| vs erf-GELU < 1e-3
__device__ __forceinline__ float gelu_f(float x) {
  float x2 = x * x;
  float m = __builtin_fmaf(0.07135481283f, x2, 1.595769122f);
  float e = __expf(-x * m);
  return x * __builtin_amdgcn_rcpf(1.0f + e);
}

// barrier that does NOT drain vmcnt: LDS writes visible, global loads stay in
// flight. sched_barrier(0) pins codegen around the inline-asm waitcnt (rule 18).
__device__ __forceinline__ void lds_barrier() {
  asm volatile("s_waitcnt lgkmcnt(0)" ::: "memory");
  __builtin_amdgcn_sched_barrier(0);
  __builtin_amdgcn_s_barrier();
}

// ---------------------------------------------------------------------------
// Weight packing: src row-major [k][col] f32 -> bf16 [k/8][col][k%8]
// ushort offsets: W1p 0 (64Ki), W2p 65536 (16Ki), W3p 81920 (16Ki),
// Winp 98304 (64Ki), Woutp 163840 (64Ki). Total 448 KB.
// ---------------------------------------------------------------------------
__global__ __launch_bounds__(256) void pack_w(
    const float* __restrict__ W1, const float* __restrict__ W2,
    const float* __restrict__ W3, const float* __restrict__ Win,
    const float* __restrict__ Wout, ushort* __restrict__ ws) {
  int id = blockIdx.x * 256 + threadIdx.x;
  if (id < 65536) {                       // W1: K=512, ncol=128
    int t = id, k = t >> 7, c = t & 127;
    ws[(((k >> 3) << 7) + c) * 8 + (k & 7)] = f2bf(W1[t]);
  } else if (id < 81920) {                // W2
    int t = id - 65536, k = t >> 7, c = t & 127;
    ws[65536 + (((k >> 3) << 7) + c) * 8 + (k & 7)] = f2bf(W2[t]);
  } else if (id < 98304) {                // W3
    int t = id - 81920, k = t >> 7, c = t & 127;
    ws[81920 + (((k >> 3) << 7) + c) * 8 + (k & 7)] = f2bf(W3[t]);
  } else if (id < 163840) {               // Win: K=128, ncol=512
    int t = id - 98304, k = t >> 9, c = t & 511;
    ws[98304 + (((k >> 3) << 9) + c) * 8 + (k & 7)] = f2bf(Win[t]);
  } else {                                // Wout: K=512, ncol=128
    int t = id - 163840, k = t >> 7, c = t & 127;
    ws[163840 + (((k >> 3) << 7) + c) * 8 + (k & 7)] = f2bf(Wout[t]);
  }
}

// ---------- msg3 helpers (round-8 validated, byte-exact) ----------

// issue global loads of 64-col chunk c of pair p: 8 f32/thread (2 dwordx4)
__device__ __forceinline__ void issue_chunk(const float* __restrict__ hE,
    int p, int c, int tid, int N, float4& a, float4& b) {
  const int r = tid >> 3;              // row 0..63 (node*32 + edge)
  const int cb = (tid & 7) * 8;        // col base within chunk
  const int node = r >> 5, e = r & 31;
  int n = 2 * p + node;
  if (n >= N) n = 0;
  const float* g = hE + ((size_t)n * NK + e) * NC + c * 64 + cb;
  const float4* gp = reinterpret_cast<const float4*>(g);
  a = gp[0];
  b = gp[1];
}

// convert staged regs -> 64x64 bf16 tile (granule XOR-swizzled)
__device__ __forceinline__ void convert_regs(ushort* __restrict__ sC, int tid,
    float4 a, float4 b, bool zz) {
  const int r = tid >> 3, cg = tid & 7;
  short8v v = zz ? (short8v){0, 0, 0, 0, 0, 0, 0, 0} : pack8(a, b);
  st8(sC + r * 64 + ((cg ^ (r & 7)) << 3), v);
}

// MFMA over one 64-col chunk j (k global [128+j*64, 128+(j+1)*64))
__device__ __forceinline__ void mfma_chunk64(const ushort* __restrict__ sC,
    const ushort* __restrict__ W1p, int j, f32x4 acc[4],
    int g, int lr, int outcol) {
#pragma unroll
  for (int jj = 0; jj < 2; ++jj) {
    short8v bfr = ld8(W1p + (((16 + j * 8 + jj * 4 + g) * 128) + outcol) * 8);
    const int akg = jj * 4 + g;
#pragma unroll
    for (int rt = 0; rt < 4; ++rt) {
      const int row = rt * 16 + lr;
      short8v af = ld8(sC + row * 64 + ((akg ^ (row & 7)) << 3));
      acc[rt] = MFMA16(af, bfr, acc[rt]);
    }
  }
}

// 128-wide helpers for H1/H2 (granule space 16, row&15 swizzle)
__device__ __forceinline__ void mfma_chunk(const ushort* __restrict__ buf,
    const ushort* __restrict__ Wp, int ktBase, f32x4 acc[4],
    int g, int lr, int outcol) {
#pragma unroll
  for (int j = 0; j < 4; ++j) {
    short8v bfr = ld8(Wp + (((ktBase + j) * 4 + g) * 128 + outcol) * 8);
    const int kcg = j * 4 + g;
#pragma unroll
    for (int rt = 0; rt < 4; ++rt) {
      const int row = rt * 16 + lr;
      short8v af = ld8(buf + row * 128 + ((kcg ^ (row & 15)) << 3));
      acc[rt] = MFMA16(af, bfr, acc[rt]);
    }
  }
}

__device__ __forceinline__ void epi_store(ushort* __restrict__ buf,
    const f32x4 acc[4], const float* __restrict__ bias, int outcol, int g) {
  const float bs = bias[outcol];
#pragma unroll
  for (int rt = 0; rt < 4; ++rt)
#pragma unroll
    for (int i = 0; i < 4; ++i) {
      const int rr = rt * 16 + g * 4 + i;
      buf[rr * 128 + ((((outcol >> 3) ^ (rr & 15)) << 3) | (outcol & 7))] =
          f2bf(gelu_f(acc[rt][i] + bs));
    }
}

// ---------------------------------------------------------------------------
// Message kernel v3 (round-8 validated, best observed): one node-pair per
// block, 512 threads, 5000 blocks. 6x64-col chunks, reg-staged (2x8 f32
// banks), lgkm-only barriers keep next-next chunk's loads in flight.
// Fresh blocks (NOT persistent — persistence regressed 4x in rounds 3-14).
// ---------------------------------------------------------------------------
__global__ __launch_bounds__(512, 4) void msg3(
    const float* __restrict__ hV, const float* __restrict__ hE,
    const float* __restrict__ mAtt, const ushort* __restrict__ wsu,
    const float* __restrict__ b1, const float* __restrict__ b2,
    const float* __restrict__ b3, const float* __restrict__ g1,
    const float* __restrict__ be1, float* __restrict__ hmidf,
    ushort* __restrict__ hmidb, int N) {
  const ushort* W1p = wsu;
  const ushort* W2p = wsu + 65536;
  const ushort* W3p = wsu + 81920;

  __shared__ ushort sC[2][4096];    // 2 x 8KB bf16 chunk tiles; reused as H1
  __shared__ ushort sH2[8192];      // 16KB H2
  __shared__ ushort sHV[256];       // 2 nodes x 128 bf16
  __shared__ float  sDh[256];
  __shared__ float  sRed[16];

  const int tid = threadIdx.x;
  const int w = tid >> 6, lane = tid & 63;
  const int g = lane >> 4, lr = lane & 15;
  const int outcol = (w << 4) + lr;
  const int p = blockIdx.x;
  const bool zz = (2 * p + ((tid >> 3) >> 5)) >= N;   // staging-row validity

  float4 eA, eB, oA, oB;   // two 8-f32 staging banks (even/odd chunks)

  // ---- prologue: get memory going immediately ----
  issue_chunk(hE, p, 0, tid, N, eA, eB);
  issue_chunk(hE, p, 1, tid, N, oA, oB);
  if (tid < 32) {
    const int nd = tid >> 4, c8 = tid & 15;
    const int n = 2 * p + nd;
    const int ncl = n < N ? n : 0;
    const float4* hp = reinterpret_cast<const float4*>(hV + (size_t)ncl * NH + c8 * 8);
    float4 h0 = hp[0], h1 = hp[1];
    if (n >= N) { h0 = (float4){0.f, 0.f, 0.f, 0.f}; h1 = h0; }
    st8(sHV + nd * 128 + c8 * 8, pack8(h0, h1));
  }
  convert_regs(sC[0], tid, eA, eB, zz);   // c0 (compiler waits on eA/eB)
  lds_barrier();

  f32x4 acc[4];
#pragma unroll
  for (int rt = 0; rt < 4; ++rt) acc[rt] = (f32x4){0.f, 0.f, 0.f, 0.f};

  // ===== layer-1 hV part (k 0..127, granules 0..15) =====
#pragma unroll
  for (int kt = 0; kt < 4; ++kt) {
    short8v bfr = ld8(W1p + ((kt * 4 + g) * 128 + outcol) * 8);
    short8v a0 = ld8(sHV + kt * 32 + g * 8);
    short8v a1 = ld8(sHV + 128 + kt * 32 + g * 8);
    acc[0] = MFMA16(a0, bfr, acc[0]);
    acc[1] = MFMA16(a0, bfr, acc[1]);
    acc[2] = MFMA16(a1, bfr, acc[2]);
    acc[3] = MFMA16(a1, bfr, acc[3]);
  }

  // ===== layer-1 h_E chunks, software-pipelined =====
  // j=0: consume c0; convert c1; issue c2
  issue_chunk(hE, p, 2, tid, N, eA, eB);
  mfma_chunk64(sC[0], W1p, 0, acc, g, lr, outcol);
  convert_regs(sC[1], tid, oA, oB, zz);
  lds_barrier();
  // j=1: consume c1; convert c2; issue c3
  issue_chunk(hE, p, 3, tid, N, oA, oB);
  mfma_chunk64(sC[1], W1p, 1, acc, g, lr, outcol);
  convert_regs(sC[0], tid, eA, eB, zz);
  lds_barrier();
  // j=2: consume c2; convert c3; issue c4
  issue_chunk(hE, p, 4, tid, N, eA, eB);
  mfma_chunk64(sC[0], W1p, 2, acc, g, lr, outcol);
  convert_regs(sC[1], tid, oA, oB, zz);
  lds_barrier();
  // j=3: consume c3; convert c4; issue c5
  issue_chunk(hE, p, 5, tid, N, oA, oB);
  mfma_chunk64(sC[1], W1p, 3, acc, g, lr, outcol);
  convert_regs(sC[0], tid, eA, eB, zz);
  lds_barrier();
  // j=4: consume c4; convert c5
  mfma_chunk64(sC[0], W1p, 4, acc, g, lr, outcol);
  convert_regs(sC[1], tid, oA, oB, zz);
  lds_barrier();
  // j=5: consume c5
  mfma_chunk64(sC[1], W1p, 5, acc, g, lr, outcol);
  __syncthreads();

  // ===== layer-1 epilogue: H1 -> sC region (as [64][128]) =====
  ushort* sH1 = &sC[0][0];
  epi_store(sH1, acc, b1, outcol, g);
  __syncthreads();

  // ===== layer 2: H1 -> H2 =====
#pragma unroll
  for (int rt = 0; rt < 4; ++rt) acc[rt] = (f32x4){0.f, 0.f, 0.f, 0.f};
  mfma_chunk(sH1, W2p, 0, acc, g, lr, outcol);
  epi_store(sH2, acc, b2, outcol, g);
  __syncthreads();

  // ===== layer 3: H2 -> masked edge-sum =====
#pragma unroll
  for (int rt = 0; rt < 4; ++rt) acc[rt] = (f32x4){0.f, 0.f, 0.f, 0.f};
  mfma_chunk(sH2, W3p, 0, acc, g, lr, outcol);
  {
    const float bias = b3[outcol];
    float ns0 = 0.f, ns1 = 0.f;
#pragma unroll
    for (int rt = 0; rt < 4; ++rt) {
      const int nd = rt >> 1;
      float s = 0.f;
#pragma unroll
      for (int i = 0; i < 4; ++i) {
        const int e2 = (rt & 1) * 16 + g * 4 + i;
        const float m =
            (2 * p + nd < N) ? mAtt[(size_t)(2 * p + nd) * NK + e2] : 0.f;
        s += (acc[rt][i] + bias) * m;
      }
      s += __shfl_xor(s, 16, 64);
      s += __shfl_xor(s, 32, 64);
      if (rt < 2) ns0 += s; else ns1 += s;
    }
    if (g == 0) { sDh[outcol] = ns0; sDh[128 + outcol] = ns1; }
  }
  __syncthreads();

  // ===== LN1 + h_mid store =====
  float x_ln = 0.f;
  if (tid < 256) {
    const int nd = tid >> 7, i = tid & 127;
    const int gn = 2 * p + nd;
    if (gn < N)
      x_ln = hV[(size_t)gn * NH + i] + sDh[nd * NH + i] * (1.f / 30.f);
    float s = x_ln, qv = x_ln * x_ln;
#pragma unroll
    for (int d = 1; d < 64; d <<= 1) {
      s += __shfl_xor(s, d, 64);
      qv += __shfl_xor(qv, d, 64);
    }
    if (lane == 0) { sRed[w * 2] = s; sRed[w * 2 + 1] = qv; }
  }
  __syncthreads();
  if (tid < 256) {
    const int nd = tid >> 7, i = tid & 127;
    const int gn = 2 * p + nd;
    if (gn < N) {
      const int wb = nd * 2;
      const float s = sRed[wb * 2] + sRed[wb * 2 + 2];
      const float qv = sRed[wb * 2 + 1] + sRed[wb * 2 + 3];
      const float mean = s * (1.f / 128.f);
      const float var = qv * (1.f / 128.f) - mean * mean;
      const float y = (x_ln - mean) * rsqrtf(var + 1e-5f) * g1[i] + be1[i];
      hmidf[(size_t)gn * NH + i] = y;
      hmidb[(size_t)gn * NH + i] = f2bf(y);
    }
  }
}

// ---------------------------------------------------------------------------
// FFN kernel: FFN_NPB(=20) nodes / block (500 blocks -> ~1.95/CU, balanced),
// 512 threads (8 waves), 32-row tile structure with n<N guards on the
// padded rows. Weight reads amortize over 20 nodes (12.8 KB/node).
// LDS: sX 8KB + sHf 32KB + sY 16.9KB = ~57KB -> 2 blocks/CU.
// ---------------------------------------------------------------------------
__global__ __launch_bounds__(512, 4) void ffn32(
    const ushort* __restrict__ wsu, const float* __restrict__ binf,
    const float* __restrict__ boutf, const float* __restrict__ g2,
    const float* __restrict__ be2, const float* __restrict__ maskV,
    const float* __restrict__ hmidf, const ushort* __restrict__ hmidb,
    float* __restrict__ out, int N) {
  const ushort* Winp = wsu + 98304;
  const ushort* Woutp = wsu + 163840;

  __shared__ ushort sX[32 * 128];     // 8KB
  __shared__ ushort sHf[32 * 512];    // 32KB
  __shared__ float  sY[32 * 132];     // 16.9KB

  const int tid = threadIdx.x;
  const int w = tid >> 6, lane = tid & 63;
  const int g = lane >> 4, lr = lane & 15;
  const int n0 = blockIdx.x * FFN_NPB;
  const int nEnd = n0 + FFN_NPB;       // rows [FFN_NPB,32) are padding

  // stage h_mid (bf16) -> sX swizzled (512 chunks, one per thread)
  {
    const int rr = tid >> 4, c8 = tid & 15;
    const int n = n0 + rr;
    short8v v = {0, 0, 0, 0, 0, 0, 0, 0};
    if (rr < FFN_NPB && n < N) v = ld8(hmidb + (size_t)n * NH + c8 * 8);
    st8(sX + rr * 128 + ((c8 ^ (rr & 15)) << 3), v);
  }
  __syncthreads();

  // -------- layer in: [32,128] @ Win -> gelu -> sHf [32,512] --------
  // wave w owns cols [w*64, w*64+64): 4 col-tiles; a-frags reused across them
  {
    f32x4 accI[4][2];
#pragma unroll
    for (int ct = 0; ct < 4; ++ct) {
      accI[ct][0] = (f32x4){0.f, 0.f, 0.f, 0.f};
      accI[ct][1] = accI[ct][0];
    }
#pragma unroll
    for (int kt = 0; kt < 4; ++kt) {
      const int kcg = kt * 4 + g;
      short8v a0 = ld8(sX + lr * 128 + ((kcg ^ lr) << 3));
      short8v a1 = ld8(sX + (16 + lr) * 128 + ((kcg ^ lr) << 3));
#pragma unroll
      for (int ct = 0; ct < 4; ++ct) {
        const int col = (w << 6) + ct * 16 + lr;
        short8v b = ld8(Winp + (kcg * 512 + col) * 8);
        accI[ct][0] = MFMA16(a0, b, accI[ct][0]);
        accI[ct][1] = MFMA16(a1, b, accI[ct][1]);
      }
    }
#pragma unroll
    for (int ct = 0; ct < 4; ++ct) {
      const int col = (w << 6) + ct * 16 + lr;
      const float bi = binf[col];
      const int c8 = col >> 3;
#pragma unroll
      for (int rt = 0; rt < 2; ++rt)
#pragma unroll
        for (int i = 0; i < 4; ++i) {
          const int rr = rt * 16 + g * 4 + i;
          sHf[rr * 512 + (((c8 ^ (rr & 15)) << 3) | (col & 7))] =
              f2bf(gelu_f(accI[ct][rt][i] + bi));
        }
    }
  }
  __syncthreads();

  // -------- layer out: [32,512] @ Wout (wave w -> cols [w*16, w*16+16)) ----
  f32x4 o0 = (f32x4){0.f, 0.f, 0.f, 0.f}, o1 = o0;
  const int ocol = (w << 4) + lr;
#pragma unroll
  for (int kt = 0; kt < 16; ++kt) {
    const int kcg = kt * 4 + g;                 // [0,64)
    short8v b = ld8(Woutp + (kcg * 128 + ocol) * 8);
    short8v a0 = ld8(sHf + lr * 512 + ((kcg ^ lr) << 3));
    short8v a1 = ld8(sHf + (16 + lr) * 512 + ((kcg ^ lr) << 3));
    o0 = MFMA16(a0, b, o0);
    o1 = MFMA16(a1, b, o1);
  }
  // epilogue: + bias + residual -> sY
  {
    const float bo = boutf[ocol];
#pragma unroll
    for (int rt = 0; rt < 2; ++rt) {
      const f32x4 oo = rt ? o1 : o0;
#pragma unroll
      for (int i = 0; i < 4; ++i) {
        const int rr = rt * 16 + g * 4 + i;
        const int n = n0 + rr;
        const float resid = (rr < FFN_NPB && n < N) ? hmidf[(size_t)n * NH + ocol] : 0.f;
        sY[rr * 132 + ocol] = oo[i] + bo + resid;
      }
    }
  }
  __syncthreads();

  // -------- LN2 + mask + store (16 threads per row, 8 cols each) --------
  {
    const int rr = tid >> 4, qq = tid & 15;
    const int n = n0 + rr;
    float vals[8];
    float s = 0.f, qs = 0.f;
    const float* yr = sY + rr * 132 + qq * 8;
#pragma unroll
    for (int j = 0; j < 8; ++j) { float x = yr[j]; vals[j] = x; s += x; qs += x * x; }
    s += __shfl_xor(s, 1, 64);  qs += __shfl_xor(qs, 1, 64);
    s += __shfl_xor(s, 2, 64);  qs += __shfl_xor(qs, 2, 64);
    s += __shfl_xor(s, 4, 64);  qs += __shfl_xor(qs, 4, 64);
    s += __shfl_xor(s, 8, 64);  qs += __shfl_xor(qs, 8, 64);
    const float mean = s * (1.f / 128.f);
    const float var = qs * (1.f / 128.f) - mean * mean;
    const float rs = rsqrtf(var + 1e-5f);
    if (rr < FFN_NPB && n < N) {
      const float mv = maskV[n];
#pragma unroll
      for (int j = 0; j < 8; ++j) {
        const int col = qq * 8 + j;
        out[(size_t)n * NH + col] = ((vals[j] - mean) * rs * g2[col] + be2[col]) * mv;
      }
    }
  }
}

extern "C" void kernel_launch(void* const* d_in, const int* in_sizes, int n_in,
                              void* d_out, int out_size, void* d_ws, size_t ws_size,
                              hipStream_t stream) {
  const float* hV   = (const float*)d_in[0];
  const float* hE   = (const float*)d_in[1];
  const float* mV   = (const float*)d_in[2];
  const float* mAtt = (const float*)d_in[3];
  const float* W1   = (const float*)d_in[4];
  const float* b1   = (const float*)d_in[5];
  const float* W2   = (const float*)d_in[6];
  const float* b2   = (const float*)d_in[7];
  const float* W3   = (const float*)d_in[8];
  const float* b3   = (const float*)d_in[9];
  const float* g1   = (const float*)d_in[10];
  const float* be1  = (const float*)d_in[11];
  const float* Win  = (const float*)d_in[12];
  const float* binf = (const float*)d_in[13];
  const float* Wout = (const float*)d_in[14];
  const float* bout = (const float*)d_in[15];
  const float* g2   = (const float*)d_in[16];
  const float* be2  = (const float*)d_in[17];

  const int N = in_sizes[0] / NH;

  ushort* wsu = (ushort*)d_ws;                         // packed weights: 448 KB
  float*  hmidf = (float*)((char*)d_ws + 458752);      // N*128 f32
  ushort* hmidb = (ushort*)((char*)d_ws + 458752 + (size_t)N * NH * 4);  // N*128 bf16

  pack_w<<<896, 256, 0, stream>>>(W1, W2, W3, Win, Wout, wsu);

  const int pairs = (N + 1) / 2;
  msg3<<<pairs, 512, 0, stream>>>(hV, hE, mAtt, wsu, b1, b2, b3, g1, be1,
                                  hmidf, hmidb, N);
  ffn32<<<(N + FFN_NPB - 1) / FFN_NPB, 512, 0, stream>>>(
      wsu, binf, bout, g2, be2, mV, hmidf, hmidb, (float*)d_out, N);
  (void)n_in; (void)out_size; (void)ws_size;
}

// Round 17
// 160.777 us; speedup vs baseline: 1.0332x; 1.0332x over previous
//
#include <hip/hip_runtime.h>
#include <hip/hip_bf16.h>

#define NH 128   // hidden
#define NC 384   // edge feature dim
#define NK 32    // neighbors

typedef __attribute__((ext_vector_type(8))) short short8v;   // 8 bf16
typedef __attribute__((ext_vector_type(4))) float f32x4;

#define MFMA16(a, b, c) __builtin_amdgcn_mfma_f32_16x16x32_bf16((a), (b), (c), 0, 0, 0)

__device__ __forceinline__ ushort f2bf(float x) {
  __hip_bfloat16 h = __float2bfloat16(x);   // RNE; packs to v_cvt_pk_bf16_f32
  ushort u;
  __builtin_memcpy(&u, &h, 2);
  return u;
}

__device__ __forceinline__ short8v ld8(const ushort* p) {
  return *reinterpret_cast<const short8v*>(p);
}
__device__ __forceinline__ void st8(ushort* p, short8v v) {
  *reinterpret_cast<short8v*>(p) = v;
}

__device__ __forceinline__ short8v pack8(float4 a, float4 b) {
  short8v v;
  v[0] = (short)f2bf(a.x); v[1] = (short)f2bf(a.y);
  v[2] = (short)f2bf(a.z); v[3] = (short)f2bf(a.w);
  v[4] = (short)f2bf(b.x); v[5] = (short)f2bf(b.y);
  v[6] = (short)f2bf(b.z); v[7] = (short)f2bf(b.w);
  return v;
}

// gelu(x) = x * sigmoid(x*(1.5958 + 0.07136 x^2)); |err| vs erf-GELU < 1e-3
__device__ __forceinline__ float gelu_f(float x) {
  float x2 = x * x;
  float m = __builtin_fmaf(0.07135481283f, x2, 1.595769122f);
  float e = __expf(-x * m);
  return x * __builtin_amdgcn_rcpf(1.0f + e);
}

// barrier that does NOT drain vmcnt: LDS writes visible, global loads stay in
// flight. sched_barrier(0) pins codegen around the inline-asm waitcnt (rule 18).
__device__ __forceinline__ void lds_barrier() {
  asm volatile("s_waitcnt lgkmcnt(0)" ::: "memory");
  __builtin_amdgcn_sched_barrier(0);
  __builtin_amdgcn_s_barrier();
}

// ---------------------------------------------------------------------------
// Weight packing: src row-major [k][col] f32 -> bf16 [k/8][col][k%8]
// ushort offsets: W1p 0 (64Ki), W2p 65536 (16Ki), W3p 81920 (16Ki),
// Winp 98304 (64Ki), Woutp 163840 (64Ki). Total 448 KB.
// ---------------------------------------------------------------------------
__global__ __launch_bounds__(256) void pack_w(
    const float* __restrict__ W1, const float* __restrict__ W2,
    const float* __restrict__ W3, const float* __restrict__ Win,
    const float* __restrict__ Wout, ushort* __restrict__ ws) {
  int id = blockIdx.x * 256 + threadIdx.x;
  if (id < 65536) {                       // W1: K=512, ncol=128
    int t = id, k = t >> 7, c = t & 127;
    ws[(((k >> 3) << 7) + c) * 8 + (k & 7)] = f2bf(W1[t]);
  } else if (id < 81920) {                // W2
    int t = id - 65536, k = t >> 7, c = t & 127;
    ws[65536 + (((k >> 3) << 7) + c) * 8 + (k & 7)] = f2bf(W2[t]);
  } else if (id < 98304) {                // W3
    int t = id - 81920, k = t >> 7, c = t & 127;
    ws[81920 + (((k >> 3) << 7) + c) * 8 + (k & 7)] = f2bf(W3[t]);
  } else if (id < 163840) {               // Win: K=128, ncol=512
    int t = id - 98304, k = t >> 9, c = t & 511;
    ws[98304 + (((k >> 3) << 9) + c) * 8 + (k & 7)] = f2bf(Win[t]);
  } else {                                // Wout: K=512, ncol=128
    int t = id - 163840, k = t >> 7, c = t & 127;
    ws[163840 + (((k >> 3) << 7) + c) * 8 + (k & 7)] = f2bf(Wout[t]);
  }
}

// ---------- msg8 helpers (msg3 pattern widened to 4 nodes / 128 rows) ------

// issue global loads of 64-col chunk c of quad q: 16 f32/thread (4 dwordx4)
__device__ __forceinline__ void issue_chunk4(const float* __restrict__ hE,
    int q, int c, int tid, int N,
    float4& a, float4& b, float4& cc, float4& d) {
  const int r = tid >> 2;              // row 0..127 (node*32 + edge)
  const int cb = (tid & 3) * 16;       // col base within chunk
  const int node = r >> 5, e = r & 31;
  int n = 4 * q + node;
  if (n >= N) n = 0;
  const float* g = hE + ((size_t)n * NK + e) * NC + c * 64 + cb;
  const float4* gp = reinterpret_cast<const float4*>(g);
  a = gp[0]; b = gp[1]; cc = gp[2]; d = gp[3];
}

// convert staged regs -> [128][64] bf16 tile (granule XOR-swizzled, as msg3)
__device__ __forceinline__ void convert_regs4(ushort* __restrict__ sC, int tid,
    float4 a, float4 b, float4 cc, float4 d, bool zz) {
  const int r = tid >> 2, cg0 = (tid & 3) * 2;
  short8v v0, v1;
  if (zz) {
    v0 = (short8v){0, 0, 0, 0, 0, 0, 0, 0};
    v1 = v0;
  } else {
    v0 = pack8(a, b);
    v1 = pack8(cc, d);
  }
  st8(sC + r * 64 + ((cg0 ^ (r & 7)) << 3), v0);
  st8(sC + r * 64 + (((cg0 + 1) ^ (r & 7)) << 3), v1);
}

// MFMA over one 64-col chunk j (k granules 16+8j..16+8j+7), 8 row-tiles
__device__ __forceinline__ void mfma_chunk64_8(const ushort* __restrict__ sC,
    const ushort* __restrict__ W1p, int j, f32x4 acc[8],
    int g, int lr, int outcol) {
#pragma unroll
  for (int jj = 0; jj < 2; ++jj) {
    short8v bfr = ld8(W1p + (((16 + j * 8 + jj * 4 + g) * 128) + outcol) * 8);
    const int akg = jj * 4 + g;
#pragma unroll
    for (int rt = 0; rt < 8; ++rt) {
      const int row = rt * 16 + lr;
      short8v af = ld8(sC + row * 64 + ((akg ^ (row & 7)) << 3));
      acc[rt] = MFMA16(af, bfr, acc[rt]);
    }
  }
}

// 128-wide helper for H1/H2 [128][128] (granule space 16, row&15 swizzle)
__device__ __forceinline__ void mfma_chunk_8(const ushort* __restrict__ buf,
    const ushort* __restrict__ Wp, f32x4 acc[8], int g, int lr, int outcol) {
#pragma unroll
  for (int j = 0; j < 4; ++j) {
    short8v bfr = ld8(Wp + ((j * 4 + g) * 128 + outcol) * 8);
    const int kcg = j * 4 + g;
#pragma unroll
    for (int rt = 0; rt < 8; ++rt) {
      const int row = rt * 16 + lr;
      short8v af = ld8(buf + row * 128 + ((kcg ^ (row & 15)) << 3));
      acc[rt] = MFMA16(af, bfr, acc[rt]);
    }
  }
}

__device__ __forceinline__ void epi_store_8(ushort* __restrict__ buf,
    const f32x4 acc[8], const float* __restrict__ bias, int outcol, int g) {
  const float bs = bias[outcol];
#pragma unroll
  for (int rt = 0; rt < 8; ++rt)
#pragma unroll
    for (int i = 0; i < 4; ++i) {
      const int rr = rt * 16 + g * 4 + i;
      buf[rr * 128 + ((((outcol >> 3) ^ (rr & 15)) << 3) | (outcol & 7))] =
          f2bf(gelu_f(acc[rt][i] + bs));
    }
}

// ---------------------------------------------------------------------------
// Message kernel v8: FOUR nodes per block, 512 threads, 2500 blocks.
// msg3's validated in-block pipeline (6x64-col chunks, 2 reg banks, lgkm-only
// barriers) at 2x tile height: mem per block doubles, serial tail grows
// sub-linearly -> tail fraction ~40%->~25%; W1/W2/W3 L2 traffic halves.
// Fresh blocks, zero cross-block state. LDS 67KB -> 2 blocks/CU.
// sC(32KB) is reused as H1 [128][128] after layer 1; sH2 32KB.
// ---------------------------------------------------------------------------
__global__ __launch_bounds__(512, 4) void msg8(
    const float* __restrict__ hV, const float* __restrict__ hE,
    const float* __restrict__ mAtt, const ushort* __restrict__ wsu,
    const float* __restrict__ b1, const float* __restrict__ b2,
    const float* __restrict__ b3, const float* __restrict__ g1,
    const float* __restrict__ be1, float* __restrict__ hmidf,
    ushort* __restrict__ hmidb, int N) {
  const ushort* W1p = wsu;
  const ushort* W2p = wsu + 65536;
  const ushort* W3p = wsu + 81920;

  __shared__ ushort sC[2][8192];    // 2 x 16KB chunk tiles; reused as H1 (32KB)
  __shared__ ushort sH2[16384];     // 32KB H2 [128][128]
  __shared__ ushort sHV[512];       // 4 nodes x 128 bf16
  __shared__ float  sDh[512];       // 4 nodes x 128
  __shared__ float  sRed[16];       // 8 waves x {s,q}

  const int tid = threadIdx.x;
  const int w = tid >> 6, lane = tid & 63;
  const int g = lane >> 4, lr = lane & 15;
  const int outcol = (w << 4) + lr;
  const int q = blockIdx.x;
  const bool zz = (4 * q + (tid >> 7)) >= N;   // staging-row node validity

  float4 eA, eB, eC, eD, oA, oB, oC, oD;   // two 16-f32 staging banks

  // ---- prologue: get memory going immediately ----
  issue_chunk4(hE, q, 0, tid, N, eA, eB, eC, eD);
  issue_chunk4(hE, q, 1, tid, N, oA, oB, oC, oD);
  if (tid < 64) {
    const int nd = tid >> 4, c8 = tid & 15;
    const int n = 4 * q + nd;
    const int ncl = n < N ? n : 0;
    const float4* hp = reinterpret_cast<const float4*>(hV + (size_t)ncl * NH + c8 * 8);
    float4 h0 = hp[0], h1 = hp[1];
    if (n >= N) { h0 = (float4){0.f, 0.f, 0.f, 0.f}; h1 = h0; }
    st8(sHV + nd * 128 + c8 * 8, pack8(h0, h1));
  }
  convert_regs4(sC[0], tid, eA, eB, eC, eD, zz);   // c0
  lds_barrier();

  f32x4 acc[8];
#pragma unroll
  for (int rt = 0; rt < 8; ++rt) acc[rt] = (f32x4){0.f, 0.f, 0.f, 0.f};

  // ===== layer-1 hV part (k 0..127): one MFMA per node, copied to both
  // row-tiles of that node (rows within a node are identical) =====
#pragma unroll
  for (int kt = 0; kt < 4; ++kt) {
    short8v bfr = ld8(W1p + ((kt * 4 + g) * 128 + outcol) * 8);
#pragma unroll
    for (int nd = 0; nd < 4; ++nd) {
      short8v a0 = ld8(sHV + nd * 128 + kt * 32 + g * 8);
      acc[nd * 2] = MFMA16(a0, bfr, acc[nd * 2]);
    }
  }
#pragma unroll
  for (int nd = 0; nd < 4; ++nd) acc[nd * 2 + 1] = acc[nd * 2];

  // ===== layer-1 h_E chunks, software-pipelined (lgkm-only barriers) =====
  // j=0: consume c0; convert c1; issue c2
  issue_chunk4(hE, q, 2, tid, N, eA, eB, eC, eD);
  mfma_chunk64_8(sC[0], W1p, 0, acc, g, lr, outcol);
  convert_regs4(sC[1], tid, oA, oB, oC, oD, zz);
  lds_barrier();
  // j=1: consume c1; convert c2; issue c3
  issue_chunk4(hE, q, 3, tid, N, oA, oB, oC, oD);
  mfma_chunk64_8(sC[1], W1p, 1, acc, g, lr, outcol);
  convert_regs4(sC[0], tid, eA, eB, eC, eD, zz);
  lds_barrier();
  // j=2: consume c2; convert c3; issue c4
  issue_chunk4(hE, q, 4, tid, N, eA, eB, eC, eD);
  mfma_chunk64_8(sC[0], W1p, 2, acc, g, lr, outcol);
  convert_regs4(sC[1], tid, oA, oB, oC, oD, zz);
  lds_barrier();
  // j=3: consume c3; convert c4; issue c5
  issue_chunk4(hE, q, 5, tid, N, oA, oB, oC, oD);
  mfma_chunk64_8(sC[1], W1p, 3, acc, g, lr, outcol);
  convert_regs4(sC[0], tid, eA, eB, eC, eD, zz);
  lds_barrier();
  // j=4: consume c4; convert c5
  mfma_chunk64_8(sC[0], W1p, 4, acc, g, lr, outcol);
  convert_regs4(sC[1], tid, oA, oB, oC, oD, zz);
  lds_barrier();
  // j=5: consume c5
  mfma_chunk64_8(sC[1], W1p, 5, acc, g, lr, outcol);
  __syncthreads();

  // ===== layer-1 epilogue: H1 -> sC region (as [128][128], 32KB) =====
  ushort* sH1 = &sC[0][0];
  epi_store_8(sH1, acc, b1, outcol, g);
  __syncthreads();

  // ===== layer 2: H1 -> H2 =====
#pragma unroll
  for (int rt = 0; rt < 8; ++rt) acc[rt] = (f32x4){0.f, 0.f, 0.f, 0.f};
  mfma_chunk_8(sH1, W2p, acc, g, lr, outcol);
  epi_store_8(sH2, acc, b2, outcol, g);
  __syncthreads();

  // ===== layer 3: H2 -> masked edge-sum =====
#pragma unroll
  for (int rt = 0; rt < 8; ++rt) acc[rt] = (f32x4){0.f, 0.f, 0.f, 0.f};
  mfma_chunk_8(sH2, W3p, acc, g, lr, outcol);
  {
    const float bias = b3[outcol];
    float ns[4];
#pragma unroll
    for (int nd = 0; nd < 4; ++nd) {
      float s = 0.f;
#pragma unroll
      for (int half = 0; half < 2; ++half)
#pragma unroll
        for (int i = 0; i < 4; ++i) {
          const int e2 = half * 16 + g * 4 + i;
          const float m =
              (4 * q + nd < N) ? mAtt[(size_t)(4 * q + nd) * NK + e2] : 0.f;
          s += (acc[nd * 2 + half][i] + bias) * m;
        }
      s += __shfl_xor(s, 16, 64);
      s += __shfl_xor(s, 32, 64);
      ns[nd] = s;
    }
    if (g == 0) {
#pragma unroll
      for (int nd = 0; nd < 4; ++nd) sDh[nd * 128 + outcol] = ns[nd];
    }
  }
  __syncthreads();

  // ===== LN1 + h_mid store (512 threads: node = tid>>7) =====
  float x_ln = 0.f;
  {
    const int nd = tid >> 7, i = tid & 127;
    const int gn = 4 * q + nd;
    if (gn < N)
      x_ln = hV[(size_t)gn * NH + i] + sDh[nd * 128 + i] * (1.f / 30.f);
    float s = x_ln, qv = x_ln * x_ln;
#pragma unroll
    for (int d = 1; d < 64; d <<= 1) {
      s += __shfl_xor(s, d, 64);
      qv += __shfl_xor(qv, d, 64);
    }
    if (lane == 0) { sRed[w * 2] = s; sRed[w * 2 + 1] = qv; }
  }
  __syncthreads();
  {
    const int nd = tid >> 7, i = tid & 127;
    const int gn = 4 * q + nd;
    if (gn < N) {
      const float s = sRed[nd * 4] + sRed[nd * 4 + 2];
      const float qv = sRed[nd * 4 + 1] + sRed[nd * 4 + 3];
      const float mean = s * (1.f / 128.f);
      const float var = qv * (1.f / 128.f) - mean * mean;
      const float y = (x_ln - mean) * rsqrtf(var + 1e-5f) * g1[i] + be1[i];
      hmidf[(size_t)gn * NH + i] = y;
      hmidb[(size_t)gn * NH + i] = f2bf(y);
    }
  }
}

// ---------------------------------------------------------------------------
// FFN kernel (round-15 validated, best observed): 32 nodes / block
// (313 blocks), 512 threads (8 waves). LDS ~57KB -> 2 blocks/CU.
// ---------------------------------------------------------------------------
__global__ __launch_bounds__(512, 4) void ffn32(
    const ushort* __restrict__ wsu, const float* __restrict__ binf,
    const float* __restrict__ boutf, const float* __restrict__ g2,
    const float* __restrict__ be2, const float* __restrict__ maskV,
    const float* __restrict__ hmidf, const ushort* __restrict__ hmidb,
    float* __restrict__ out, int N) {
  const ushort* Winp = wsu + 98304;
  const ushort* Woutp = wsu + 163840;

  __shared__ ushort sX[32 * 128];     // 8KB
  __shared__ ushort sHf[32 * 512];    // 32KB
  __shared__ float  sY[32 * 132];     // 16.9KB

  const int tid = threadIdx.x;
  const int w = tid >> 6, lane = tid & 63;
  const int g = lane >> 4, lr = lane & 15;
  const int n0 = blockIdx.x * 32;

  // stage h_mid (bf16) -> sX swizzled (512 chunks, one per thread)
  {
    const int rr = tid >> 4, c8 = tid & 15;
    const int n = n0 + rr;
    short8v v = {0, 0, 0, 0, 0, 0, 0, 0};
    if (n < N) v = ld8(hmidb + (size_t)n * NH + c8 * 8);
    st8(sX + rr * 128 + ((c8 ^ (rr & 15)) << 3), v);
  }
  __syncthreads();

  // -------- layer in: [32,128] @ Win -> gelu -> sHf [32,512] --------
  {
    f32x4 accI[4][2];
#pragma unroll
    for (int ct = 0; ct < 4; ++ct) {
      accI[ct][0] = (f32x4){0.f, 0.f, 0.f, 0.f};
      accI[ct][1] = accI[ct][0];
    }
#pragma unroll
    for (int kt = 0; kt < 4; ++kt) {
      const int kcg = kt * 4 + g;
      short8v a0 = ld8(sX + lr * 128 + ((kcg ^ lr) << 3));
      short8v a1 = ld8(sX + (16 + lr) * 128 + ((kcg ^ lr) << 3));
#pragma unroll
      for (int ct = 0; ct < 4; ++ct) {
        const int col = (w << 6) + ct * 16 + lr;
        short8v b = ld8(Winp + (kcg * 512 + col) * 8);
        accI[ct][0] = MFMA16(a0, b, accI[ct][0]);
        accI[ct][1] = MFMA16(a1, b, accI[ct][1]);
      }
    }
#pragma unroll
    for (int ct = 0; ct < 4; ++ct) {
      const int col = (w << 6) + ct * 16 + lr;
      const float bi = binf[col];
      const int c8 = col >> 3;
#pragma unroll
      for (int rt = 0; rt < 2; ++rt)
#pragma unroll
        for (int i = 0; i < 4; ++i) {
          const int rr = rt * 16 + g * 4 + i;
          sHf[rr * 512 + (((c8 ^ (rr & 15)) << 3) | (col & 7))] =
              f2bf(gelu_f(accI[ct][rt][i] + bi));
        }
    }
  }
  __syncthreads();

  // -------- layer out: [32,512] @ Wout (wave w -> cols [w*16, w*16+16)) ----
  f32x4 o0 = (f32x4){0.f, 0.f, 0.f, 0.f}, o1 = o0;
  const int ocol = (w << 4) + lr;
#pragma unroll
  for (int kt = 0; kt < 16; ++kt) {
    const int kcg = kt * 4 + g;                 // [0,64)
    short8v b = ld8(Woutp + (kcg * 128 + ocol) * 8);
    short8v a0 = ld8(sHf + lr * 512 + ((kcg ^ lr) << 3));
    short8v a1 = ld8(sHf + (16 + lr) * 512 + ((kcg ^ lr) << 3));
    o0 = MFMA16(a0, b, o0);
    o1 = MFMA16(a1, b, o1);
  }
  // epilogue: + bias + residual -> sY
  {
    const float bo = boutf[ocol];
#pragma unroll
    for (int rt = 0; rt < 2; ++rt) {
      const f32x4 oo = rt ? o1 : o0;
#pragma unroll
      for (int i = 0; i < 4; ++i) {
        const int rr = rt * 16 + g * 4 + i;
        const int n = n0 + rr;
        const float resid = (n < N) ? hmidf[(size_t)n * NH + ocol] : 0.f;
        sY[rr * 132 + ocol] = oo[i] + bo + resid;
      }
    }
  }
  __syncthreads();

  // -------- LN2 + mask + store (16 threads per row, 8 cols each) --------
  {
    const int rr = tid >> 4, qq = tid & 15;
    const int n = n0 + rr;
    float vals[8];
    float s = 0.f, qs = 0.f;
    const float* yr = sY + rr * 132 + qq * 8;
#pragma unroll
    for (int j = 0; j < 8; ++j) { float x = yr[j]; vals[j] = x; s += x; qs += x * x; }
    s += __shfl_xor(s, 1, 64);  qs += __shfl_xor(qs, 1, 64);
    s += __shfl_xor(s, 2, 64);  qs += __shfl_xor(qs, 2, 64);
    s += __shfl_xor(s, 4, 64);  qs += __shfl_xor(qs, 4, 64);
    s += __shfl_xor(s, 8, 64);  qs += __shfl_xor(qs, 8, 64);
    const float mean = s * (1.f / 128.f);
    const float var = qs * (1.f / 128.f) - mean * mean;
    const float rs = rsqrtf(var + 1e-5f);
    if (n < N) {
      const float mv = maskV[n];
#pragma unroll
      for (int j = 0; j < 8; ++j) {
        const int col = qq * 8 + j;
        out[(size_t)n * NH + col] = ((vals[j] - mean) * rs * g2[col] + be2[col]) * mv;
      }
    }
  }
}

extern "C" void kernel_launch(void* const* d_in, const int* in_sizes, int n_in,
                              void* d_out, int out_size, void* d_ws, size_t ws_size,
                              hipStream_t stream) {
  const float* hV   = (const float*)d_in[0];
  const float* hE   = (const float*)d_in[1];
  const float* mV   = (const float*)d_in[2];
  const float* mAtt = (const float*)d_in[3];
  const float* W1   = (const float*)d_in[4];
  const float* b1   = (const float*)d_in[5];
  const float* W2   = (const float*)d_in[6];
  const float* b2   = (const float*)d_in[7];
  const float* W3   = (const float*)d_in[8];
  const float* b3   = (const float*)d_in[9];
  const float* g1   = (const float*)d_in[10];
  const float* be1  = (const float*)d_in[11];
  const float* Win  = (const float*)d_in[12];
  const float* binf = (const float*)d_in[13];
  const float* Wout = (const float*)d_in[14];
  const float* bout = (const float*)d_in[15];
  const float* g2   = (const float*)d_in[16];
  const float* be2  = (const float*)d_in[17];

  const int N = in_sizes[0] / NH;

  ushort* wsu = (ushort*)d_ws;                         // packed weights: 448 KB
  float*  hmidf = (float*)((char*)d_ws + 458752);      // N*128 f32
  ushort* hmidb = (ushort*)((char*)d_ws + 458752 + (size_t)N * NH * 4);  // N*128 bf16

  pack_w<<<896, 256, 0, stream>>>(W1, W2, W3, Win, Wout, wsu);

  const int quads = (N + 3) / 4;
  msg8<<<quads, 512, 0, stream>>>(hV, hE, mAtt, wsu, b1, b2, b3, g1, be1,
                                  hmidf, hmidb, N);
  ffn32<<<(N + 31) / 32, 512, 0, stream>>>(wsu, binf, bout, g2, be2, mV,
                                           hmidf, hmidb, (float*)d_out, N);
  (void)n_in; (void)out_size; (void)ws_size;
}